// Round 4
// baseline (6063.839 us; speedup 1.0000x reference)
//
#include <hip/hip_runtime.h>

typedef short   bf16x8 __attribute__((ext_vector_type(8)));
typedef unsigned short u16x4 __attribute__((ext_vector_type(4)));
typedef unsigned short u16x8 __attribute__((ext_vector_type(8)));
typedef float   f32x16 __attribute__((ext_vector_type(16)));

constexpr int NSUB  = 8;
constexpr int NCODE = 256;
constexpr int SDIM  = 96;
constexpr int EMB   = NSUB * SDIM;          // 768
constexpr int TILE_ROWS = 128;
constexpr int ROWS_PER_BLK = 1024;
constexpr int NTILES = ROWS_PER_BLK / TILE_ROWS;   // 8
constexpr float C_SHIFT = 192.0f;   // positivity shift: score+192>0 since ||x||^2<384 whp
constexpr float THR = 0.05f;        // recheck trigger; >> 2*(trunc 0.004 + mfma 0.001)

constexpr int    CB_UNITS      = 8 * 6 * 2 * 64;                 // 6144 x 16B per subspace
constexpr size_t WS_FRAG_BYTES = (size_t)NSUB * CB_UNITS * 16;   // 786432
constexpr size_t WS_NEEDED     = WS_FRAG_BYTES + (size_t)NSUB * NCODE * 4;

__device__ __forceinline__ unsigned short f2bf(float v) {
    unsigned u = __builtin_bit_cast(unsigned, v);
    u = u + 0x7FFFu + ((u >> 16) & 1u);          // RNE
    return (unsigned short)(u >> 16);
}
__device__ __forceinline__ float bf2f(unsigned short h) {
    unsigned u = ((unsigned)h) << 16;
    return __builtin_bit_cast(float, u);
}
__device__ __forceinline__ unsigned umin2(unsigned a, unsigned b) { return a < b ? a : b; }
__device__ __forceinline__ unsigned umax2(unsigned a, unsigned b) { return a > b ? a : b; }

// X LDS swizzle: unit u (1 KiB each), byte offset off in [0,1024).
// XOR bits 4..6 by (u&7): reads (uniform u per instr) stay conflict-free;
// writes (u varies across lanes via s,h) spread across banks.
__device__ __forceinline__ int xaddr(int u, int off) {
    return u * 1024 + (off ^ ((u & 7) << 4));
}

// ---------------- pre-kernel: pack codebook into ws ----------------
// frag unit u = ((t*6+s)*2+h)*64 + l : code=t*32+(l&31), k0=s*16+(l>>5)*8,
// value = h==0 ? hi : lo of (-cb). wsc2 = 0.5*||c||^2 + C_SHIFT (fp64).
__global__ __launch_bounds__(256) void pq_prep(const float* __restrict__ cb,
                                               unsigned short* __restrict__ wsf,
                                               float* __restrict__ wsc2)
{
    const int m   = (int)blockIdx.x;
    const int tid = (int)threadIdx.x;
    {
        const float* c = cb + ((size_t)m * NCODE + tid) * SDIM;
        double s = 0.0;
        for (int k = 0; k < SDIM; ++k) { double v = (double)c[k]; s += v * v; }
        wsc2[m * NCODE + tid] = (float)(0.5 * s + (double)C_SHIFT);
    }
    for (int i = 0; i < 24; ++i) {
        int u  = i * 256 + tid;
        int l  = u & 63;
        int c6 = u >> 6;
        int h  = c6 & 1; c6 >>= 1;
        int s  = c6 % 6;
        int t  = c6 / 6;
        int code = t * 32 + (l & 31);
        int k0   = s * 16 + (l >> 5) * 8;
        const float* src = cb + (size_t)m * NCODE * SDIM + (size_t)code * SDIM + k0;
        u16x8 o;
        #pragma unroll
        for (int j = 0; j < 8; ++j) {
            float v = -src[j];
            unsigned short hb = f2bf(v);
            o[j] = (h == 0) ? hb : f2bf(v - bf2f(hb));
        }
        *(u16x8*)(wsf + ((size_t)m * CB_UNITS + u) * 8) = o;
    }
}

// ---------------- main kernel: codebook-in-registers, x in LDS ----------------
__global__ __launch_bounds__(256, 2) void pq_mfma2(
    const float* __restrict__ emb,
    const float* __restrict__ cb,
    const unsigned short* __restrict__ wsf,
    const float* __restrict__ wsc2,
    float* __restrict__ out,
    int nrows)
{
    __shared__ char  xbuf[48 * 1024];      // 48 units x 1KiB, swizzled
    __shared__ float c2s[NCODE];
    __shared__ uint2 mergebuf[4 * TILE_ROWS];
    __shared__ int   trig_cnt;
    __shared__ int   trig_rows[TILE_ROWS];

    const int tid  = (int)threadIdx.x;
    const int w    = tid >> 6;
    const int lane = tid & 63;
    const int m    = (int)(blockIdx.x & 7);
    const int rb   = (int)(blockIdx.x >> 3);
    const int row0 = rb * ROWS_PER_BLK;
    const int hib  = lane >> 5;

    // ---- prologue: codebook fragments (64 codes per wave) into registers ----
    bf16x8 cbh[2][6], cbl[2][6];
    {
        const unsigned short* wb = wsf + (size_t)m * CB_UNITS * 8;
        #pragma unroll
        for (int t2 = 0; t2 < 2; ++t2) {
            int tg = w * 2 + t2;
            #pragma unroll
            for (int s = 0; s < 6; ++s) {
                cbh[t2][s] = *(const bf16x8*)(wb + (size_t)(((tg * 6 + s) * 2 + 0) * 64 + lane) * 8);
                cbl[t2][s] = *(const bf16x8*)(wb + (size_t)(((tg * 6 + s) * 2 + 1) * 64 + lane) * 8);
            }
        }
        c2s[tid] = wsc2[m * NCODE + tid];
    }

    float4 xf[12];
    auto issue_x = [&](int t) {
        #pragma unroll
        for (int ii = 0; ii < 12; ++ii) {
            int Q = ii * 256 + tid;
            int r = Q / 24, f = Q % 24;
            int gr = row0 + t * TILE_ROWS + r;
            if (gr >= nrows) gr = nrows - 1;
            xf[ii] = *(const float4*)(emb + (size_t)gr * EMB + m * SDIM + f * 4);
        }
    };
    issue_x(0);

    for (int it = 0; it < NTILES; ++it) {
        const int rowt0 = row0 + it * TILE_ROWS;

        // ---- P1: convert xf -> bf16 hi/lo fragments in LDS (swizzled) ----
        #pragma unroll
        for (int ii = 0; ii < 12; ++ii) {
            int Q = ii * 256 + tid;
            int r = Q / 24, f = Q % 24;
            int s = f >> 2, kh = (f >> 1) & 1, j0 = f & 1;
            int g = r >> 5, lp = (r & 31) + 32 * kh;
            float v[4] = { xf[ii].x, xf[ii].y, xf[ii].z, xf[ii].w };
            u16x4 hi4, lo4;
            #pragma unroll
            for (int e = 0; e < 4; ++e) {
                unsigned short hb = f2bf(v[e]);
                hi4[e] = hb;
                lo4[e] = f2bf(v[e] - bf2f(hb));
            }
            int uh = (g * 6 + s) * 2;
            int off = lp * 16 + j0 * 8;
            *(u16x4*)(xbuf + xaddr(uh, off))     = hi4;
            *(u16x4*)(xbuf + xaddr(uh + 1, off)) = lo4;
        }
        __syncthreads();                            // bar_A: X ready, mergebuf free

        // ---- P2: MFMA + packed-key epilogue ----
        if (tid == 0) trig_cnt = 0;
        #pragma unroll
        for (int g = 0; g < 4; ++g) {
            bf16x8 xh[6], xl[6];
            #pragma unroll
            for (int s = 0; s < 6; ++s) {
                xh[s] = *(const bf16x8*)(xbuf + xaddr((g * 6 + s) * 2,     lane * 16));
                xl[s] = *(const bf16x8*)(xbuf + xaddr((g * 6 + s) * 2 + 1, lane * 16));
            }
            f32x16 a0, a1;
            #pragma unroll
            for (int rq = 0; rq < 4; ++rq) {
                float4 q0 = *(const float4*)&c2s[(w * 2 + 0) * 32 + rq * 8 + hib * 4];
                float4 q1 = *(const float4*)&c2s[(w * 2 + 1) * 32 + rq * 8 + hib * 4];
                a0[rq*4+0]=q0.x; a0[rq*4+1]=q0.y; a0[rq*4+2]=q0.z; a0[rq*4+3]=q0.w;
                a1[rq*4+0]=q1.x; a1[rq*4+1]=q1.y; a1[rq*4+2]=q1.z; a1[rq*4+3]=q1.w;
            }
            #pragma unroll
            for (int s = 0; s < 6; ++s) {
                a0 = __builtin_amdgcn_mfma_f32_32x32x16_bf16(cbh[0][s], xh[s], a0, 0, 0, 0);
                a1 = __builtin_amdgcn_mfma_f32_32x32x16_bf16(cbh[1][s], xh[s], a1, 0, 0, 0);
                a0 = __builtin_amdgcn_mfma_f32_32x32x16_bf16(cbh[0][s], xl[s], a0, 0, 0, 0);
                a1 = __builtin_amdgcn_mfma_f32_32x32x16_bf16(cbh[1][s], xl[s], a1, 0, 0, 0);
                a0 = __builtin_amdgcn_mfma_f32_32x32x16_bf16(cbl[0][s], xh[s], a0, 0, 0, 0);
                a1 = __builtin_amdgcn_mfma_f32_32x32x16_bf16(cbl[1][s], xh[s], a1, 0, 0, 0);
            }
            // packed keys: (score-bits & ~0xFF) | code  — positive floats sort as uints
            unsigned m1 = ~0u, m2 = ~0u;
            #pragma unroll
            for (int rq = 0; rq < 4; ++rq) {
                #pragma unroll
                for (int rr = 0; rr < 4; ++rr) {
                    {
                        unsigned idx = (unsigned)((w * 2 + 0) * 32 + rq * 8 + hib * 4 + rr);
                        unsigned kb = (__builtin_bit_cast(unsigned, a0[rq*4+rr]) & 0xFFFFFF00u) | idx;
                        unsigned mx = umax2(m1, kb);
                        m2 = umin2(m2, mx); m1 = umin2(m1, kb);
                    }
                    {
                        unsigned idx = (unsigned)((w * 2 + 1) * 32 + rq * 8 + hib * 4 + rr);
                        unsigned kb = (__builtin_bit_cast(unsigned, a1[rq*4+rr]) & 0xFFFFFF00u) | idx;
                        unsigned mx = umax2(m1, kb);
                        m2 = umin2(m2, mx); m1 = umin2(m1, kb);
                    }
                }
            }
            unsigned om1 = (unsigned)__shfl_xor((int)m1, 32);
            unsigned om2 = (unsigned)__shfl_xor((int)m2, 32);
            unsigned mm1 = umin2(m1, om1);
            unsigned mm2 = umin2(umax2(m1, om1), umin2(m2, om2));
            if (lane < 32)
                mergebuf[w * TILE_ROWS + g * 32 + lane] = uint2{ mm1, mm2 };
        }
        __syncthreads();                            // bar_B: mergebuf ready, X consumed

        // ---- P3: issue next x loads; merge across waves; write non-triggered rows ----
        if (it + 1 < NTILES) issue_x(it + 1);
        {
            int r = tid >> 1, half = tid & 1;
            int grow = rowt0 + r;
            if (grow < nrows) {
                uint2 p0 = mergebuf[0 * TILE_ROWS + r];
                uint2 p1 = mergebuf[1 * TILE_ROWS + r];
                uint2 p2 = mergebuf[2 * TILE_ROWS + r];
                uint2 p3 = mergebuf[3 * TILE_ROWS + r];
                unsigned lo01 = umin2(p0.x, p1.x), hi01 = umax2(p0.x, p1.x);
                unsigned lo23 = umin2(p2.x, p3.x), hi23 = umax2(p2.x, p3.x);
                unsigned m1g  = umin2(lo01, lo23);
                unsigned seca = umin2(umin2(hi01, hi23), umax2(lo01, lo23));
                unsigned m2g  = umin2(umin2(seca, umin2(p0.y, p1.y)), umin2(p2.y, p3.y));
                float s1 = __builtin_bit_cast(float, m1g & 0xFFFFFF00u);
                float s2 = __builtin_bit_cast(float, m2g & 0xFFFFFF00u);
                int   k  = (int)(m1g & 0xFFu);
                if (s2 - s1 < THR) {
                    if (!half) { int p = atomicAdd(&trig_cnt, 1); trig_rows[p] = r; }
                } else {
                    const float* src = cb + ((size_t)m * NCODE + k) * SDIM + half * 48;
                    float* dst = out + (size_t)grow * EMB + m * SDIM + half * 48;
                    #pragma unroll
                    for (int ii = 0; ii < 12; ++ii)
                        *(float4*)(dst + ii * 4) = *(const float4*)(src + ii * 4);
                }
            }
        }
        __syncthreads();                            // bar_C: trig list final

        // ---- P4: exact fp64 rescan for triggered rows (wave-parallel, rare) ----
        {
            int nt = trig_cnt;
            for (int j = w; j < nt; j += 4) {
                int r = trig_rows[j];
                int grow = rowt0 + r;
                const float* xr = emb + (size_t)grow * EMB + m * SDIM;
                double bd = 1e300; int bc = NCODE;
                #pragma unroll 1
                for (int q = 0; q < 4; ++q) {
                    int code = q * 64 + lane;
                    const float* cv = cb + ((size_t)m * NCODE + code) * SDIM;
                    double acc = 0.0;
                    #pragma unroll
                    for (int kk = 0; kk < SDIM; kk += 4) {
                        float4 xv = *(const float4*)(xr + kk);
                        float4 cc = *(const float4*)(cv + kk);
                        double d0 = (double)xv.x - (double)cc.x;
                        double d1 = (double)xv.y - (double)cc.y;
                        double d2 = (double)xv.z - (double)cc.z;
                        double d3 = (double)xv.w - (double)cc.w;
                        acc += d0*d0 + d1*d1 + d2*d2 + d3*d3;
                    }
                    if (acc < bd) { bd = acc; bc = code; }   // q ascending: first-min kept
                }
                #pragma unroll
                for (int off = 32; off > 0; off >>= 1) {
                    double od = __shfl_xor(bd, off);
                    int    oc = __shfl_xor(bc, off);
                    if (od < bd || (od == bd && oc < bc)) { bd = od; bc = oc; }
                }
                if (lane < 24) {
                    float4 v = *(const float4*)(cb + ((size_t)m * NCODE + bc) * SDIM + lane * 4);
                    *(float4*)(out + (size_t)grow * EMB + m * SDIM + lane * 4) = v;
                }
            }
        }
        // next P1 only touches xbuf (consumed) — bar_A next iter fences trig reuse
    }
}

// ---------------- fallback (round-2 kernel, validated) ----------------
__global__ __launch_bounds__(256) void pq_argmin_kernel(
    const float* __restrict__ emb, const float* __restrict__ cb,
    float* __restrict__ out, int nrows)
{
    const int m   = (int)(blockIdx.x & 7);
    const int row = (int)(blockIdx.x >> 3) * 256 + (int)threadIdx.x;
    const float* __restrict__ cbm = cb + (size_t)m * (NCODE * SDIM);
    __shared__ float half_c2[NCODE];
    {
        const int k = (int)threadIdx.x;
        const float* c = cbm + k * SDIM;
        float s = 0.f;
        #pragma unroll
        for (int i = 0; i < SDIM; i += 4) {
            const float4 v = *reinterpret_cast<const float4*>(c + i);
            s = fmaf(v.x, v.x, s); s = fmaf(v.y, v.y, s);
            s = fmaf(v.z, v.z, s); s = fmaf(v.w, v.w, s);
        }
        half_c2[k] = 0.5f * s;
    }
    __syncthreads();
    if (row >= nrows) return;
    float x[SDIM];
    {
        const float* xr = emb + (size_t)row * EMB + m * SDIM;
        #pragma unroll
        for (int i = 0; i < SDIM; i += 4) {
            const float4 v = *reinterpret_cast<const float4*>(xr + i);
            x[i+0] = v.x; x[i+1] = v.y; x[i+2] = v.z; x[i+3] = v.w;
        }
    }
    float best = 3.4e38f, best2 = 3.4e38f;
    int bestk = 0, bestk2 = 0;
    #pragma unroll 1
    for (int k = 0; k < NCODE; k += 4) {
        const float* c0 = cbm + (k + 0) * SDIM;
        const float* c1 = cbm + (k + 1) * SDIM;
        const float* c2 = cbm + (k + 2) * SDIM;
        const float* c3 = cbm + (k + 3) * SDIM;
        float a0 = 0.f, a1 = 0.f, a2 = 0.f, a3 = 0.f;
        #pragma unroll
        for (int i = 0; i < SDIM; i += 4) {
            const float4 v0 = *reinterpret_cast<const float4*>(c0 + i);
            const float4 v1 = *reinterpret_cast<const float4*>(c1 + i);
            const float4 v2 = *reinterpret_cast<const float4*>(c2 + i);
            const float4 v3 = *reinterpret_cast<const float4*>(c3 + i);
            a0 = fmaf(x[i+0], v0.x, a0); a0 = fmaf(x[i+1], v0.y, a0);
            a0 = fmaf(x[i+2], v0.z, a0); a0 = fmaf(x[i+3], v0.w, a0);
            a1 = fmaf(x[i+0], v1.x, a1); a1 = fmaf(x[i+1], v1.y, a1);
            a1 = fmaf(x[i+2], v1.z, a1); a1 = fmaf(x[i+3], v1.w, a1);
            a2 = fmaf(x[i+0], v2.x, a2); a2 = fmaf(x[i+1], v2.y, a2);
            a2 = fmaf(x[i+2], v2.z, a2); a2 = fmaf(x[i+3], v2.w, a2);
            a3 = fmaf(x[i+0], v3.x, a3); a3 = fmaf(x[i+1], v3.y, a3);
            a3 = fmaf(x[i+2], v3.z, a3); a3 = fmaf(x[i+3], v3.w, a3);
        }
        const float s[4] = { half_c2[k+0] - a0, half_c2[k+1] - a1,
                             half_c2[k+2] - a2, half_c2[k+3] - a3 };
        #pragma unroll
        for (int j = 0; j < 4; ++j) {
            if (s[j] < best)       { best2 = best; bestk2 = bestk; best = s[j]; bestk = k + j; }
            else if (s[j] < best2) { best2 = s[j]; bestk2 = k + j; }
        }
    }
    if (best2 - best < 0.02f) {
        const float* ca = cbm + bestk  * SDIM;
        const float* cbv = cbm + bestk2 * SDIM;
        double da = 0.0, db = 0.0;
        for (int i = 0; i < SDIM; ++i) {
            const double ea = (double)x[i] - (double)ca[i];
            const double eb = (double)x[i] - (double)cbv[i];
            da += ea * ea; db += eb * eb;
        }
        if (db < da || (db == da && bestk2 < bestk)) bestk = bestk2;
    }
    const float* cbest = cbm + bestk * SDIM;
    float* o = out + (size_t)row * EMB + m * SDIM;
    #pragma unroll
    for (int i = 0; i < SDIM; i += 4)
        *reinterpret_cast<float4*>(o + i) = *reinterpret_cast<const float4*>(cbest + i);
}

extern "C" void kernel_launch(void* const* d_in, const int* in_sizes, int n_in,
                              void* d_out, int out_size, void* d_ws, size_t ws_size,
                              hipStream_t stream) {
    const float* emb = (const float*)d_in[0];
    const float* cb  = (const float*)d_in[1];
    float* out = (float*)d_out;
    const int nrows = in_sizes[0] / EMB;    // 65536

    if (ws_size < WS_NEEDED) {
        const int rowBlocks = (nrows + 255) / 256;
        pq_argmin_kernel<<<dim3(rowBlocks * NSUB), dim3(256), 0, stream>>>(emb, cb, out, nrows);
        return;
    }

    unsigned short* wsf = (unsigned short*)d_ws;
    float* wsc2 = (float*)((char*)d_ws + WS_FRAG_BYTES);

    pq_prep<<<dim3(NSUB), dim3(256), 0, stream>>>(cb, wsf, wsc2);

    const int nb = (nrows + ROWS_PER_BLK - 1) / ROWS_PER_BLK;   // 64
    pq_mfma2<<<dim3(nb * NSUB), dim3(256), 0, stream>>>(emb, cb, wsf, wsc2, out, nrows);
}